// Round 7
// baseline (522.209 us; speedup 1.0000x reference)
//
#include <hip/hip_runtime.h>
#include <stdint.h>

#define DEVI __device__ __forceinline__

typedef __attribute__((ext_vector_type(8))) short short8;
typedef __attribute__((ext_vector_type(4))) float f32x4;
typedef __attribute__((ext_vector_type(4))) unsigned int u32x4;

static constexpr int Bn = 2;
static constexpr int Tn = 2048;
static constexpr int Cn = 2048;
static constexpr int NH = 16;
static constexpr int HD = 128;
static constexpr int Kdim = 2048;

DEVI unsigned short f2bf(float f) {
  union { float f; unsigned u; } v; v.f = f;
  return (unsigned short)((v.u + 0x7FFFu + ((v.u >> 16) & 1u)) >> 16);
}

DEVI void gload_lds16(const void* g, void* l) {
  __builtin_amdgcn_global_load_lds(
      (const __attribute__((address_space(1))) void*)g,
      (__attribute__((address_space(3))) void*)l, 16, 0, 0);
}

// ---------------- cast fp32 -> bf16 (RNE), all 5 matrices in one dispatch --
__global__ __launch_bounds__(256) void cast5_kernel(
    const float* __restrict__ s0, const float* __restrict__ s1,
    const float* __restrict__ s2, const float* __restrict__ s3,
    const float* __restrict__ s4,
    unsigned short* __restrict__ d0, unsigned short* __restrict__ d1,
    unsigned short* __restrict__ d2, unsigned short* __restrict__ d3,
    unsigned short* __restrict__ d4, int n0, int nw) {
  const int w = blockIdx.y;
  const float* src = (w == 0) ? s0 : (w == 1) ? s1 : (w == 2) ? s2 : (w == 3) ? s3 : s4;
  unsigned short* dst = (w == 0) ? d0 : (w == 1) ? d1 : (w == 2) ? d2 : (w == 3) ? d3 : d4;
  const int n = (w == 0) ? n0 : nw;
  int idx = (blockIdx.x * blockDim.x + threadIdx.x) * 4;
  const int stride = gridDim.x * blockDim.x * 4;
  for (; idx < n; idx += stride) {
    f32x4 f = *(const f32x4*)(src + idx);
    unsigned short o[4];
    o[0] = f2bf(f[0]); o[1] = f2bf(f[1]); o[2] = f2bf(f[2]); o[3] = f2bf(f[3]);
    *(unsigned long long*)(dst + idx) = *(const unsigned long long*)o;
  }
}

// ---------------- fused QKV projection GEMM (r6 structure, unchanged) ------
__global__ __launch_bounds__(256) void gemm_qkv_fused_kernel(
    const unsigned short* __restrict__ X,
    const unsigned short* __restrict__ Wq_, const unsigned short* __restrict__ Wk_,
    const unsigned short* __restrict__ Wv_,
    const float* __restrict__ bq_, const float* __restrict__ bk_, const float* __restrict__ bv_,
    unsigned short* __restrict__ Qo, unsigned short* __restrict__ Ko,
    unsigned short* __restrict__ Vo) {
  __shared__ unsigned short As[128 * 32];
  __shared__ unsigned short Bs[128 * 32];
  const int tid = threadIdx.x;
  const int wave = tid >> 6, lane = tid & 63;
  const int wm = wave >> 1, wn = wave & 1;
  const int quad = lane >> 4, lr = lane & 15;

  const int nidx = blockIdx.x;                 // 0..47
  const int m0 = blockIdx.y * 128;
  const int sel = nidx >> 4;
  const int n0 = (nidx & 15) * 128;
  const unsigned short* W = (sel == 0) ? Wq_ : (sel == 1) ? Wk_ : Wv_;
  const float* bias = (sel == 0) ? bq_ : (sel == 1) ? bk_ : bv_;

  f32x4 acc[4][4];
  const f32x4 zero4 = {0.f, 0.f, 0.f, 0.f};
#pragma unroll
  for (int i = 0; i < 4; ++i)
#pragma unroll
    for (int j = 0; j < 4; ++j) acc[i][j] = zero4;

  const int srow = tid >> 2;
  const int scol = (((tid & 3) ^ ((srow >> 1) & 3)) * 8);
  const unsigned short* Ag = X + (size_t)(m0 + srow) * Kdim + scol;
  const unsigned short* Bg = W + (size_t)(n0 + srow) * Kdim + scol;
  unsigned short* Al = &As[tid * 8];
  unsigned short* Bl = &Bs[tid * 8];
  const int fsw = (quad ^ ((lr >> 1) & 3)) * 8;

  for (int k0 = 0; k0 < Kdim; k0 += 32) {
    gload_lds16(Ag + k0, Al);
    gload_lds16(Ag + (size_t)64 * Kdim + k0, Al + 2048);
    gload_lds16(Bg + k0, Bl);
    gload_lds16(Bg + (size_t)64 * Kdim + k0, Bl + 2048);
    __syncthreads();
    short8 af[4], bf[4];
#pragma unroll
    for (int mi = 0; mi < 4; ++mi)
      af[mi] = *(const short8*)&As[(wm * 64 + mi * 16 + lr) * 32 + fsw];
#pragma unroll
    for (int ni = 0; ni < 4; ++ni)
      bf[ni] = *(const short8*)&Bs[(wn * 64 + ni * 16 + lr) * 32 + fsw];
#pragma unroll
    for (int mi = 0; mi < 4; ++mi)
#pragma unroll
      for (int ni = 0; ni < 4; ++ni)
        acc[mi][ni] = __builtin_amdgcn_mfma_f32_16x16x32_bf16(af[mi], bf[ni], acc[mi][ni], 0, 0, 0);
    __syncthreads();
  }

  if (sel == 2) {
#pragma unroll
    for (int ni = 0; ni < 4; ++ni) {
      const int n = n0 + wn * 64 + ni * 16 + lr;
      const float bv = bias[n];
      const int h = n >> 7, d = n & 127;
#pragma unroll
      for (int mi = 0; mi < 4; ++mi) {
        const int m = m0 + wm * 64 + mi * 16 + quad * 4;
        const int b = m >> 11, t = m & 2047;
        unsigned short o4[4];
#pragma unroll
        for (int r = 0; r < 4; ++r) o4[r] = f2bf(acc[mi][ni][r] + bv);
        *(unsigned long long*)&Vo[(((size_t)(b * NH + h)) * HD + d) * Tn + t] =
            *(const unsigned long long*)o4;
      }
    }
  } else {
    unsigned short* Out = (sel == 0) ? Qo : Ko;
#pragma unroll
    for (int ni = 0; ni < 4; ++ni) {
      const int n = n0 + wn * 64 + ni * 16 + lr;
      const float bv = bias[n];
      const int h = n >> 7, d = n & 127;
#pragma unroll
      for (int mi = 0; mi < 4; ++mi) {
#pragma unroll
        for (int r = 0; r < 4; ++r) {
          const int m = m0 + wm * 64 + mi * 16 + quad * 4 + r;
          const int b = m >> 11, t = m & 2047;
          Out[(((size_t)(b * NH + h)) * Tn + t) * HD + d] = f2bf(acc[mi][ni][r] + bv);
        }
      }
    }
  }
}

// ---------------- output projection GEMM (r6 structure, unchanged) ---------
__global__ __launch_bounds__(256) void gemm_proj_kernel(
    const unsigned short* __restrict__ Aall,
    const unsigned short* __restrict__ W,
    const float* __restrict__ bias,
    float* __restrict__ Y) {
  __shared__ unsigned short As[128 * 32];
  __shared__ unsigned short Bs[128 * 32];
  const int tid = threadIdx.x;
  const int wave = tid >> 6, lane = tid & 63;
  const int wm = wave >> 1, wn = wave & 1;
  const int quad = lane >> 4, lr = lane & 15;

  const int m0 = blockIdx.y * 128, n0 = blockIdx.x * 128;
  const int bz = blockIdx.z;
  const unsigned short* A = Aall + (size_t)bz * Cn * Tn;

  f32x4 acc[4][4];
  const f32x4 zero4 = {0.f, 0.f, 0.f, 0.f};
#pragma unroll
  for (int i = 0; i < 4; ++i)
#pragma unroll
    for (int j = 0; j < 4; ++j) acc[i][j] = zero4;

  const int srow = tid >> 2;
  const int scol = (((tid & 3) ^ ((srow >> 1) & 3)) * 8);
  const unsigned short* Ag = A + (size_t)(m0 + srow) * Kdim + scol;
  const unsigned short* Bg = W + (size_t)(n0 + srow) * Kdim + scol;
  unsigned short* Al = &As[tid * 8];
  unsigned short* Bl = &Bs[tid * 8];
  const int fsw = (quad ^ ((lr >> 1) & 3)) * 8;

  for (int k0 = 0; k0 < Kdim; k0 += 32) {
    gload_lds16(Ag + k0, Al);
    gload_lds16(Ag + (size_t)64 * Kdim + k0, Al + 2048);
    gload_lds16(Bg + k0, Bl);
    gload_lds16(Bg + (size_t)64 * Kdim + k0, Bl + 2048);
    __syncthreads();
    short8 af[4], bf[4];
#pragma unroll
    for (int mi = 0; mi < 4; ++mi)
      af[mi] = *(const short8*)&As[(wm * 64 + mi * 16 + lr) * 32 + fsw];
#pragma unroll
    for (int ni = 0; ni < 4; ++ni)
      bf[ni] = *(const short8*)&Bs[(wn * 64 + ni * 16 + lr) * 32 + fsw];
#pragma unroll
    for (int mi = 0; mi < 4; ++mi)
#pragma unroll
      for (int ni = 0; ni < 4; ++ni)
        acc[mi][ni] = __builtin_amdgcn_mfma_f32_16x16x32_bf16(af[mi], bf[ni], acc[mi][ni], 0, 0, 0);
    __syncthreads();
  }

#pragma unroll
  for (int ni = 0; ni < 4; ++ni) {
    const int n = n0 + wn * 64 + ni * 16 + lr;
    const float bv = bias[n];
#pragma unroll
    for (int mi = 0; mi < 4; ++mi) {
#pragma unroll
      for (int r = 0; r < 4; ++r) {
        const int m = m0 + wm * 64 + mi * 16 + quad * 4 + r;
        Y[((size_t)bz * Tn + m) * Cn + n] = acc[mi][ni][r] + bv;
      }
    }
  }
}

// ---------------- flash attention v3 ---------------------------------------
// Dual-tile chunk sharing: block j owns q-tiles jA=j and jB=15-j; one loop
// over key-chunks 0..jB stages K/V once and feeds both tiles (tile A while
// c<=jA). Unpadded Ks/Vs with XOR chunk swizzle (phys = c ^ (row&15)) ->
// global_load_lds staging + 2-way-free frag reads. QK^T computed as S^T
// (mfma(kf,qf)): lane then holds 4 consecutive keys per q-col -> packed
// ds_write_b64 P-writes (truncating bf16; bias cancels in P/sum ratio).
constexpr int PST = 136;
DEVI void attn_tile_chunk(
    const unsigned short* Ks, const unsigned short* Vs, unsigned short* Pw,
    const short8 qf[2][4], f32x4 (*oacc)[9], int q0w, int k0, bool diag,
    int quad, int lr) {
  const float SL = 0.08838834764831845f * 1.4426950408889634f;  // scale*log2e
  const f32x4 zero4 = {0.f, 0.f, 0.f, 0.f};
  // S^T = K Q^T over 8 key-tiles, processed in pairs (dep distance 4)
#pragma unroll
  for (int np = 0; np < 4; ++np) {
    short8 kf[2][4];
#pragma unroll
    for (int j = 0; j < 2; ++j)
#pragma unroll
      for (int ks = 0; ks < 4; ++ks)
        kf[j][ks] = *(const short8*)&Ks[((np * 2 + j) * 16 + lr) * 128 +
                                        (((ks * 4 + quad) ^ lr) * 8)];
    f32x4 s[2][2];
#pragma unroll
    for (int j = 0; j < 2; ++j)
#pragma unroll
      for (int mi = 0; mi < 2; ++mi) s[j][mi] = zero4;
#pragma unroll
    for (int ks = 0; ks < 4; ++ks)
#pragma unroll
      for (int j = 0; j < 2; ++j)
#pragma unroll
        for (int mi = 0; mi < 2; ++mi)
          s[j][mi] = __builtin_amdgcn_mfma_f32_16x16x32_bf16(kf[j][ks], qf[mi][ks], s[j][mi], 0, 0, 0);
#pragma unroll
    for (int j = 0; j < 2; ++j)
#pragma unroll
      for (int mi = 0; mi < 2; ++mi) {
        const int nt = np * 2 + j;
        if (diag) {
          const int q = q0w + mi * 16 + lr;
#pragma unroll
          for (int r = 0; r < 4; ++r) {
            const int key = k0 + nt * 16 + quad * 4 + r;
            if (key > q) s[j][mi][r] = -3.0e38f;
          }
        }
        union { float f; unsigned u; } a0, a1, a2, a3;
        a0.f = __builtin_amdgcn_exp2f(s[j][mi][0] * SL);
        a1.f = __builtin_amdgcn_exp2f(s[j][mi][1] * SL);
        a2.f = __builtin_amdgcn_exp2f(s[j][mi][2] * SL);
        a3.f = __builtin_amdgcn_exp2f(s[j][mi][3] * SL);
        const unsigned lo = (a0.u >> 16) | (a1.u & 0xffff0000u);
        const unsigned hi = (a2.u >> 16) | (a3.u & 0xffff0000u);
        const unsigned long long pv = (unsigned long long)lo | ((unsigned long long)hi << 32);
        *(unsigned long long*)&Pw[(mi * 16 + lr) * PST + nt * 16 + quad * 4] = pv;
      }
  }
  // O += P V   (nd==8 = ones rows -> row-sum)
#pragma unroll
  for (int kt = 0; kt < 4; ++kt) {
    short8 pf[2];
#pragma unroll
    for (int mi = 0; mi < 2; ++mi)
      pf[mi] = *(const short8*)&Pw[(mi * 16 + lr) * PST + kt * 32 + quad * 8];
#pragma unroll
    for (int nd = 0; nd < 9; ++nd) {
      short8 vf = *(const short8*)&Vs[(nd * 16 + lr) * 128 + (((kt * 4 + quad) ^ lr) * 8)];
#pragma unroll
      for (int mi = 0; mi < 2; ++mi)
        oacc[mi][nd] = __builtin_amdgcn_mfma_f32_16x16x32_bf16(pf[mi], vf, oacc[mi][nd], 0, 0, 0);
    }
  }
}

__global__ __launch_bounds__(256, 1) void attn_kernel(
    const unsigned short* __restrict__ Q,
    const unsigned short* __restrict__ K,
    const unsigned short* __restrict__ V,
    unsigned short* __restrict__ Ot) {
  __shared__ unsigned short Ks[128 * 128];
  __shared__ unsigned short Vs[144 * 128];   // rows 128..143 = ones
  __shared__ unsigned short Ps[128 * PST];

  const int tid = threadIdx.x;
  const int wave = tid >> 6, lane = tid & 63;
  const int quad = lane >> 4, lr = lane & 15;
  const int bh = blockIdx.y;

  const int jA = blockIdx.x, jB = 15 - jA;
  const int q0A = jA * 128, q0B = jB * 128;

  const unsigned short* Kp = K + (size_t)bh * Tn * HD;
  const unsigned short* Vp = V + (size_t)bh * HD * Tn;
  unsigned short* Pw = &Ps[wave * 32 * PST];

  // ones rows for the row-sum trick
  for (int i = tid; i < 16 * 128; i += 256) Vs[128 * 128 + i] = 0x3F80;

  // Q fragments for both tiles, held in registers
  short8 qfA[2][4], qfB[2][4];
  {
    const unsigned short* QpA = Q + ((size_t)bh * Tn + q0A + wave * 32) * HD;
    const unsigned short* QpB = Q + ((size_t)bh * Tn + q0B + wave * 32) * HD;
#pragma unroll
    for (int mi = 0; mi < 2; ++mi)
#pragma unroll
      for (int ks = 0; ks < 4; ++ks) {
        qfA[mi][ks] = *(const short8*)&QpA[(mi * 16 + lr) * HD + ks * 32 + quad * 8];
        qfB[mi][ks] = *(const short8*)&QpB[(mi * 16 + lr) * HD + ks * 32 + quad * 8];
      }
  }

  f32x4 oaccA[2][9], oaccB[2][9];
  const f32x4 zero4 = {0.f, 0.f, 0.f, 0.f};
#pragma unroll
  for (int mi = 0; mi < 2; ++mi)
#pragma unroll
    for (int nd = 0; nd < 9; ++nd) { oaccA[mi][nd] = zero4; oaccB[mi][nd] = zero4; }

  // staging decomposition: per instr i, this thread covers
  // row = wave*32 + i*4 + (lane>>4), phys chunk = lane&15
  const int rl = lane >> 4, ch = lane & 15;

  for (int c = 0; c <= jB; ++c) {
    const int k0 = c * 128;
#pragma unroll
    for (int i = 0; i < 8; ++i) {
      const int row = wave * 32 + i * 4 + rl;
      const int g = (ch ^ (row & 15)) * 8;
      gload_lds16(Kp + (size_t)(k0 + row) * HD + g, &Ks[row * 128 + ch * 8]);
      gload_lds16(Vp + (size_t)row * Tn + k0 + g, &Vs[row * 128 + ch * 8]);
    }
    __syncthreads();
    attn_tile_chunk(Ks, Vs, Pw, qfB, oaccB, q0B + wave * 32, k0, c == jB, quad, lr);
    if (c <= jA)
      attn_tile_chunk(Ks, Vs, Pw, qfA, oaccA, q0A + wave * 32, k0, c == jA, quad, lr);
    __syncthreads();
  }

  // epilogues: normalize, stage t-major into Ps, store O^T (B, H*D, T)
#pragma unroll 1
  for (int e = 0; e < 2; ++e) {
    const f32x4 (*oacc)[9] = e ? (const f32x4(*)[9])oaccA : (const f32x4(*)[9])oaccB;
    const int q0 = e ? q0A : q0B;
#pragma unroll
    for (int mi = 0; mi < 2; ++mi)
#pragma unroll
      for (int r = 0; r < 4; ++r) {
        const float rlv = 1.0f / oacc[mi][8][r];
        const int tl = wave * 32 + mi * 16 + quad * 4 + r;
#pragma unroll
        for (int nd = 0; nd < 8; ++nd)
          Ps[tl * PST + nd * 16 + lr] = f2bf(oacc[mi][nd][r] * rlv);
      }
    __syncthreads();
    {
      unsigned short* Od = Ot + (size_t)bh * HD * Tn + q0;
#pragma unroll
      for (int p = 0; p < 8; ++p) {
        const int d = p * 16 + (tid >> 4);
        const int t8 = (tid & 15) * 8;
        alignas(16) unsigned short v[8];
#pragma unroll
        for (int j = 0; j < 8; ++j) v[j] = Ps[(t8 + j) * PST + d];
        *(u32x4*)&Od[(size_t)d * Tn + t8] = *(const u32x4*)v;
      }
    }
    __syncthreads();
  }
}

extern "C" void kernel_launch(void* const* d_in, const int* in_sizes, int n_in,
                              void* d_out, int out_size, void* d_ws, size_t ws_size,
                              hipStream_t stream) {
  const float* x  = (const float*)d_in[0];
  const float* Wq = (const float*)d_in[1];
  const float* bq = (const float*)d_in[2];
  const float* Wk = (const float*)d_in[3];
  const float* bk = (const float*)d_in[4];
  const float* Wv = (const float*)d_in[5];
  const float* bv = (const float*)d_in[6];
  const float* Wp = (const float*)d_in[7];
  const float* bp = (const float*)d_in[8];
  float* out = (float*)d_out;

  char* ws = (char*)d_ws;
  const size_t MB = 1ull << 20;
  unsigned short* Xbf = (unsigned short*)(ws);             // 16MB
  unsigned short* Wqb = (unsigned short*)(ws + 16 * MB);   // 8MB each
  unsigned short* Wkb = (unsigned short*)(ws + 24 * MB);
  unsigned short* Wvb = (unsigned short*)(ws + 32 * MB);
  unsigned short* Wpb = (unsigned short*)(ws + 40 * MB);
  unsigned short* Qb  = (unsigned short*)(ws + 48 * MB);   // 16MB
  unsigned short* Kb  = (unsigned short*)(ws + 64 * MB);   // 16MB
  unsigned short* Vtb = (unsigned short*)(ws + 80 * MB);   // 16MB (B,H,D,T)
  unsigned short* Otb = (unsigned short*)(ws + 96 * MB);   // 16MB (B,H*D,T)

  cast5_kernel<<<dim3(512, 5), dim3(256), 0, stream>>>(
      x, Wq, Wk, Wv, Wp, Xbf, Wqb, Wkb, Wvb, Wpb, Bn * Tn * Cn, Cn * Cn);

  gemm_qkv_fused_kernel<<<dim3(48, 32), dim3(256), 0, stream>>>(
      Xbf, Wqb, Wkb, Wvb, bq, bk, bv, Qb, Kb, Vtb);

  attn_kernel<<<dim3(8, Bn * NH), dim3(256), 0, stream>>>(Qb, Kb, Vtb, Otb);

  gemm_proj_kernel<<<dim3(16, 16, 2), dim3(256), 0, stream>>>(Otb, Wpb, bp, out);
}